// Round 8
// baseline (412.174 us; speedup 1.0000x reference)
//
#include <hip/hip_runtime.h>
#include <math.h>

#define HDIM 512
#define BATCH 128

typedef _Float16 f16x8 __attribute__((ext_vector_type(8)));
typedef float f32x4 __attribute__((ext_vector_type(4)));

__device__ __forceinline__ float fast_tanh(float x) {
  float e = __expf(2.0f * x);
  return 1.0f - 2.0f / (e + 1.0f);
}

__device__ __forceinline__ void gload_lds16(const void* g, void* l) {
  __builtin_amdgcn_global_load_lds(
      (const __attribute__((address_space(1))) unsigned int*)g,
      (__attribute__((address_space(3))) unsigned int*)l, 16, 0, 0);
}

// ---------------------------------------------------------------------------
// W [512 k][512 n] fp32 -> W2 [8 kt][512 n][64 k] f16, rows (128 B) swizzled
// byte ^= (n&7)<<4  (proven conflict-free with the GEMM ds_read; R4-R6).
// grid (128, 3).
// ---------------------------------------------------------------------------
__global__ __launch_bounds__(256) void cvt_w3_kernel(
    const float* __restrict__ Wt, const float* __restrict__ Wa,
    const float* __restrict__ Wd, _Float16* __restrict__ W2t,
    _Float16* __restrict__ W2a, _Float16* __restrict__ W2d) {
  const int i = blockIdx.x * 256 + threadIdx.x;  // 512*64
  if (i >= 512 * 64) return;
  const float* W = (blockIdx.y == 0) ? Wt : (blockIdx.y == 1) ? Wa : Wd;
  _Float16* W2 = (blockIdx.y == 0) ? W2t : (blockIdx.y == 1) ? W2a : W2d;
  const int n = i & 511, g = i >> 9;
  const int kt = g >> 3, cc = g & 7;
  f16x8 h;
#pragma unroll
  for (int j = 0; j < 8; ++j)
    h[j] = (_Float16)W[(size_t)(kt * 64 + cc * 8 + j) * HDIM + n];
  char* dst = (char*)W2 + ((size_t)kt * 512 + n) * 128 + ((cc * 16) ^ ((n & 7) << 4));
  *(f16x8*)dst = h;
}

// ---------------------------------------------------------------------------
// Merged fused logit GEMM (tok / node / desc-anchor / desc-neg):
//   logits[m] += sum_n v[n] * tanh( (A@W)[m,n] + bias[n] )   (+c skipped)
// BM=256, BN=256, BK=64, 512 thr = 8 waves (2M x 4N), wave tile 128x64,
// acc 8x4, LDS 128 KB (dbuf As 2x32KB + Bs 2x32KB), 128-B rows, (row&7)<<4.
// A fp32 reg-staged (cvt/tanh in regs -> swizzled ds_write_b128, conflict-free:
// each 8-lane group covers 8 distinct 16-B slots). B via global_load_lds from
// pre-swizzled W2 (linear dest, G21).
// Pipeline per K-tile t: issue A(t+1)[8 loads]+B(t+1)[4 gloads];
//   vmcnt(12) [drains only B(t)] ; lgkmcnt(0) ; barrier ; COMPUTE(cur) ;
//   vmcnt(4) [drains A(t+1), B(t+1) stays in flight] ; WRITE_A(cur^1) ; barrier.
// Never vmcnt(0) mid-loop. logits pre-zeroed (2 n-blocks -> atomicAdd).
// ---------------------------------------------------------------------------
__global__ __launch_bounds__(512, 1) void gemm_logits_merged2_kernel(
    const float* __restrict__ A_tok, const float* __restrict__ A_node,
    const float* __restrict__ A_da, const float* __restrict__ A_dn,
    const _Float16* __restrict__ W2t, const _Float16* __restrict__ W2a,
    const _Float16* __restrict__ W2d,
    const float* __restrict__ bt, const float* __restrict__ vt,
    const float* __restrict__ ba, const float* __restrict__ va,
    const float* __restrict__ bd, const float* __restrict__ vd,
    float* __restrict__ logits_tok, float* __restrict__ logits_node,
    float* __restrict__ logits_desc) {
  __shared__ __align__(16) _Float16 As[2][256 * 64];  // 2 x 32 KB
  __shared__ __align__(16) _Float16 Bs[2][256 * 64];  // 2 x 32 KB

  const int tid = threadIdx.x;
  const int raw = (int)blockIdx.x;               // 1280 blocks
  const int swz = (raw & 7) * 160 + (raw >> 3);  // XCD-bijective (1280%8==0)

  // segments: tok 512 blocks, node 512, da 128, dn 128 (mb = local>>1, nb = local&1)
  int id, local;
  if (swz < 512)       { id = 0; local = swz; }
  else if (swz < 1024) { id = 1; local = swz - 512; }
  else if (swz < 1152) { id = 2; local = swz - 1024; }
  else                 { id = 3; local = swz - 1152; }
  const int mb = local >> 1, nb = local & 1;
  const float* A = (id == 0) ? A_tok : (id == 1) ? A_node : (id == 2) ? A_da : A_dn;
  const _Float16* W2 = (id == 0) ? W2t : (id == 1) ? W2a : W2d;
  const float* bias = (id == 0) ? bt : (id == 1) ? ba : bd;
  const float* vvec = (id == 0) ? vt : (id == 1) ? va : vd;
  float* logits = (id == 0) ? logits_tok
                : (id == 1) ? logits_node
                : (id == 2) ? logits_desc : (logits_desc + 16384);
  const bool do_tanh = (id == 1);
  const size_t m0 = (size_t)mb * 256;
  const int n0 = nb * 256;

  const int lane = tid & 63, wid = tid >> 6;
  const int tx = lane & 15, qd = lane >> 4;
  const int wm = wid >> 2;   // 0..1 -> rows wm*128..+127
  const int wn = wid & 3;    // 0..3 -> cols wn*64..+63

  // A staging: 256 rows x 64 floats; 2 thr/row, 32 floats (8 float4) each
  const int arow = tid >> 1, ahalf = tid & 1;
  const float* aptr = A + (m0 + arow) * HDIM + ahalf * 32;
  int awb[4];
#pragma unroll
  for (int q = 0; q < 4; ++q)
    awb[q] = arow * 128 + ((ahalf * 64 + q * 16) ^ ((arow & 7) << 4));

  const char* gB = (const char*)W2 + (size_t)n0 * 128;  // within each kt block

  f32x4 acc[8][4];
#pragma unroll
  for (int i = 0; i < 8; ++i)
#pragma unroll
    for (int j = 0; j < 4; ++j) acc[i][j] = (f32x4){0.f, 0.f, 0.f, 0.f};

  float4 ar0, ar1, ar2, ar3, ar4, ar5, ar6, ar7;
  auto LOAD_A = [&](int t) {
    const float4* p = (const float4*)(aptr + t * 64);
    ar0 = p[0]; ar1 = p[1]; ar2 = p[2]; ar3 = p[3];
    ar4 = p[4]; ar5 = p[5]; ar6 = p[6]; ar7 = p[7];
  };
  auto STAGE_B = [&](int buf, int t) {
    const char* b = gB + (size_t)t * 65536;
#pragma unroll
    for (int p = 0; p < 4; ++p)
      gload_lds16(b + tid * 16 + p * 8192, (char*)Bs[buf] + tid * 16 + p * 8192);
  };
  auto WRITE_A = [&](int buf) {
    float v[8];
    float4 t0 = ar0, t1 = ar1, t2 = ar2, t3 = ar3;
#pragma unroll
    for (int pair = 0; pair < 4; ++pair) {
      const float4 x = (pair == 0) ? ar0 : (pair == 1) ? ar2 : (pair == 2) ? ar4 : ar6;
      const float4 y = (pair == 0) ? ar1 : (pair == 1) ? ar3 : (pair == 2) ? ar5 : ar7;
      v[0] = x.x; v[1] = x.y; v[2] = x.z; v[3] = x.w;
      v[4] = y.x; v[5] = y.y; v[6] = y.z; v[7] = y.w;
      f16x8 h;
      if (do_tanh) {
#pragma unroll
        for (int j = 0; j < 8; ++j) h[j] = (_Float16)fast_tanh(v[j]);
      } else {
#pragma unroll
        for (int j = 0; j < 8; ++j) h[j] = (_Float16)v[j];
      }
      *(f16x8*)((char*)As[buf] + awb[pair]) = h;
    }
    (void)t0; (void)t1; (void)t2; (void)t3;
  };
  auto COMPUTE = [&](int buf) {
    f16x8 aF[8], bF[4];
#pragma unroll
    for (int ks = 0; ks < 2; ++ks) {
#pragma unroll
      for (int i = 0; i < 8; ++i) {
        const int row = wm * 128 + i * 16 + tx;
        aF[i] = *(const f16x8*)((const char*)As[buf] + row * 128 +
                                ((ks * 64 + qd * 16) ^ ((row & 7) << 4)));
      }
#pragma unroll
      for (int j = 0; j < 4; ++j) {
        const int n = wn * 64 + j * 16 + tx;
        bF[j] = *(const f16x8*)((const char*)Bs[buf] + n * 128 +
                                ((ks * 64 + qd * 16) ^ ((n & 7) << 4)));
      }
      __builtin_amdgcn_s_setprio(1);
#pragma unroll
      for (int i = 0; i < 8; ++i)
#pragma unroll
        for (int j = 0; j < 4; ++j)
          acc[i][j] = __builtin_amdgcn_mfma_f32_16x16x32_f16(aF[i], bF[j], acc[i][j], 0, 0, 0);
      __builtin_amdgcn_s_setprio(0);
    }
  };

  // prologue: A(0) loads older than B(0) gloads
  LOAD_A(0);
  STAGE_B(0, 0);
  asm volatile("s_waitcnt vmcnt(4)" ::: "memory");  // A(0) regs done, B(0) in flight
  WRITE_A(0);

#pragma unroll
  for (int t = 0; t < 8; ++t) {
    const int cur = t & 1;
    if (t < 7) {
      LOAD_A(t + 1);           // 8 loads (older)
      STAGE_B(cur ^ 1, t + 1); // 4 gloads (younger)
      // outstanding: B(t)4 oldest + A(t+1)8 + B(t+1)4 = 16 -> drain B(t) only
      asm volatile("s_waitcnt vmcnt(12)" ::: "memory");
    } else {
      asm volatile("s_waitcnt vmcnt(0)" ::: "memory");
    }
    asm volatile("s_waitcnt lgkmcnt(0)" ::: "memory");  // A ds_writes visible
    asm volatile("" ::: "memory");
    __builtin_amdgcn_s_barrier();
    asm volatile("" ::: "memory");
    COMPUTE(cur);
    if (t < 7) {
      asm volatile("s_waitcnt vmcnt(4)" ::: "memory");  // A(t+1) regs done
      WRITE_A(cur ^ 1);
    }
    asm volatile("" ::: "memory");
    __builtin_amdgcn_s_barrier();  // buf[cur] reads done before t+1 overwrites
    asm volatile("" ::: "memory");
  }

  // epilogue: t = tanh(acc + bias[n]) * v[n], reduce over this block's 256 n's
  float vv[4], bb[4];
#pragma unroll
  for (int j = 0; j < 4; ++j) {
    const int n = n0 + wn * 64 + j * 16 + tx;
    vv[j] = vvec[n];
    bb[j] = bias[n];
  }
#pragma unroll
  for (int i = 0; i < 8; ++i) {
#pragma unroll
    for (int r = 0; r < 4; ++r) {
      float s = 0.0f;
#pragma unroll
      for (int j = 0; j < 4; ++j)
        s = fmaf(vv[j], fast_tanh(acc[i][j][r] + bb[j]), s);
      s += __shfl_xor(s, 1);
      s += __shfl_xor(s, 2);
      s += __shfl_xor(s, 4);
      s += __shfl_xor(s, 8);
      if (tx == 0)
        atomicAdd(&logits[m0 + wm * 128 + i * 16 + qd * 4 + r], s);
    }
  }
}

// ---------------------------------------------------------------------------
// small/streaming kernels
// ---------------------------------------------------------------------------

__global__ void zero_kernel(float* __restrict__ p, int n) {
  const int i = blockIdx.x * 256 + threadIdx.x;
  if (i < n) p[i] = 0.0f;
}

__global__ void seg_bounds_kernel(const int* __restrict__ seg, int N,
                                  int* __restrict__ seg_start) {
  const int b = threadIdx.x;
  if (b > BATCH) return;
  int lo = 0, hi = N;
  while (lo < hi) {
    const int mid = (lo + hi) >> 1;
    if (seg[mid] < b) lo = mid + 1; else hi = mid;
  }
  seg_start[b] = lo;
}

// grid (128, 4): y=0 token (S=512), y=1 desc-anchor, y=2 desc-neg, y=3 node-seg
__global__ __launch_bounds__(256) void softmax_all_kernel(
    float* __restrict__ ltok, float* __restrict__ ldesc,
    float* __restrict__ lnode, const int* __restrict__ tlen,
    const int* __restrict__ dalen, const int* __restrict__ dnlen,
    const int* __restrict__ seg_start) {
  __shared__ float smax[4], ssum[4];
  const int b = blockIdx.x, mode = blockIdx.y, tid = threadIdx.x;
  float* l;
  int s0, s1, fill_end;
  if (mode == 0)      { l = ltok + (size_t)b * 512;          s0 = 0; s1 = tlen[b];  fill_end = 512; }
  else if (mode == 1) { l = ldesc + (size_t)b * 128;         s0 = 0; s1 = dalen[b]; fill_end = 128; }
  else if (mode == 2) { l = ldesc + 16384 + (size_t)b * 128; s0 = 0; s1 = dnlen[b]; fill_end = 128; }
  else                { l = lnode; s0 = seg_start[b]; s1 = seg_start[b + 1]; fill_end = -1; }

  float mymax = -1e30f;
  for (int s = s0 + tid; s < s1; s += 256) mymax = fmaxf(mymax, l[s]);
#pragma unroll
  for (int off = 32; off; off >>= 1) mymax = fmaxf(mymax, __shfl_xor(mymax, off));
  if ((tid & 63) == 0) smax[tid >> 6] = mymax;
  __syncthreads();
  const float bmax = fmaxf(fmaxf(smax[0], smax[1]), fmaxf(smax[2], smax[3]));
  float mysum = 0.0f;
  for (int s = s0 + tid; s < s1; s += 256) mysum += __expf(l[s] - bmax);
#pragma unroll
  for (int off = 32; off; off >>= 1) mysum += __shfl_xor(mysum, off);
  if ((tid & 63) == 0) ssum[tid >> 6] = mysum;
  __syncthreads();
  const float inv = 1.0f / (ssum[0] + ssum[1] + ssum[2] + ssum[3]);
  for (int s = s0 + tid; s < s1; s += 256) l[s] = __expf(l[s] - bmax) * inv;
  if (fill_end > 0)
    for (int s = s1 + tid; s < fill_end; s += 256) l[s] = 0.0f;
}

// grid (128, 12): c<8 token chunks, {8,9} desc-anchor, {10,11} desc-neg. fp32 src.
__global__ __launch_bounds__(256) void pool_masked_all_kernel(
    const float* __restrict__ tok_feat, const float* __restrict__ da_feat,
    const float* __restrict__ dn_feat, const float* __restrict__ ltok,
    const float* __restrict__ ldesc, float* __restrict__ tok_pool,
    float* __restrict__ da_pool, float* __restrict__ dn_pool) {
  const int b = blockIdx.x, c = blockIdx.y, tid = threadIdx.x;
  const float* feat;
  const float* w;
  float* out;
  int S, s0;
  if (c < 8)       { feat = tok_feat; S = 512; w = ltok + (size_t)b * 512;          out = tok_pool; s0 = c * 64; }
  else if (c < 10) { feat = da_feat;  S = 128; w = ldesc + (size_t)b * 128;         out = da_pool;  s0 = (c - 8) * 64; }
  else             { feat = dn_feat;  S = 128; w = ldesc + 16384 + (size_t)b * 128; out = dn_pool;  s0 = (c - 10) * 64; }
  const int h = tid * 2;
  const float* fb = feat + (size_t)b * S * HDIM + h;
  float ax = 0.0f, ay = 0.0f;
  for (int s = s0; s < s0 + 64; ++s) {
    const float wsc = w[s];
    if (wsc != 0.0f) {
      const float2 f = *(const float2*)(fb + (size_t)s * HDIM);
      ax = fmaf(wsc, f.x, ax);
      ay = fmaf(wsc, f.y, ay);
    }
  }
  atomicAdd(&out[b * HDIM + h], ax);
  atomicAdd(&out[b * HDIM + h + 1], ay);
}

// ast_pool[b,h] += sum_{n in seg b} w[n] * tanh(node_h[n,h]); grid (128, 4)
__global__ __launch_bounds__(256) void pool_seg_kernel(
    const float* __restrict__ node_h, const float* __restrict__ w,
    const int* __restrict__ seg_start, float* __restrict__ pool) {
  const int b = blockIdx.x, c = blockIdx.y, tid = threadIdx.x;
  const int h = tid * 2;
  const int s0 = seg_start[b], s1 = seg_start[b + 1];
  const int nseg = s1 - s0;
  const int chunk = (nseg + (int)gridDim.y - 1) / (int)gridDim.y;
  const int a0 = s0 + c * chunk;
  const int a1 = min(s1, a0 + chunk);
  float ax = 0.0f, ay = 0.0f;
  for (int s = a0; s < a1; ++s) {
    const float wsc = w[s];
    const float2 f = *(const float2*)(node_h + (size_t)s * HDIM + h);
    ax = fmaf(wsc, fast_tanh(f.x), ax);
    ay = fmaf(wsc, fast_tanh(f.y), ay);
  }
  atomicAdd(&pool[b * HDIM + h], ax);
  atomicAdd(&pool[b * HDIM + h + 1], ay);
}

// code-pre GEMM: parts[kb][b][n-chunk] = tanh(cat)[b][k-chunk] @ Wf[k-chunk][n-chunk]
__global__ __launch_bounds__(256) void code_gemm_kernel(
    const float* __restrict__ tok_pool, const float* __restrict__ ast_pool,
    const float* __restrict__ Wf, float* __restrict__ parts) {
  __shared__ float catS[128][65];
  __shared__ float4 wfS[64][32];
  const int nb = blockIdx.x, kb = blockIdx.y, tid = threadIdx.x;
  const int k0 = kb * 64;
  const float* src = (k0 < 512) ? (tok_pool + k0) : (ast_pool + (k0 - 512));
  for (int i = tid; i < 128 * 16; i += 256) {
    const int r = i >> 4, c4 = i & 15;
    const float4 v = *(const float4*)(src + (size_t)r * HDIM + c4 * 4);
    catS[r][c4 * 4 + 0] = fast_tanh(v.x);
    catS[r][c4 * 4 + 1] = fast_tanh(v.y);
    catS[r][c4 * 4 + 2] = fast_tanh(v.z);
    catS[r][c4 * 4 + 3] = fast_tanh(v.w);
  }
  for (int i = tid; i < 64 * 32; i += 256) {
    const int r = i >> 5, c = i & 31;
    wfS[r][c] = *(const float4*)(Wf + (size_t)(k0 + r) * HDIM + nb * 128 + c * 4);
  }
  __syncthreads();
  const int tb = tid >> 4, tn = tid & 15;
  const int b0 = tb * 8, n0l = tn * 8;
  float acc[8][8];
#pragma unroll
  for (int i = 0; i < 8; ++i)
#pragma unroll
    for (int j = 0; j < 8; ++j) acc[i][j] = 0.0f;
  for (int k = 0; k < 64; ++k) {
    float a[8];
#pragma unroll
    for (int i = 0; i < 8; ++i) a[i] = catS[b0 + i][k];
    const float4 w0 = wfS[k][tn * 2], w1 = wfS[k][tn * 2 + 1];
    const float wv[8] = {w0.x, w0.y, w0.z, w0.w, w1.x, w1.y, w1.z, w1.w};
#pragma unroll
    for (int i = 0; i < 8; ++i)
#pragma unroll
      for (int j = 0; j < 8; ++j) acc[i][j] = fmaf(a[i], wv[j], acc[i][j]);
  }
  float* dst = parts + ((size_t)kb * 128) * HDIM + nb * 128;
#pragma unroll
  for (int i = 0; i < 8; ++i) {
    const float4 o0 = {acc[i][0], acc[i][1], acc[i][2], acc[i][3]};
    const float4 o1 = {acc[i][4], acc[i][5], acc[i][6], acc[i][7]};
    *(float4*)(dst + (size_t)(b0 + i) * HDIM + n0l) = o0;
    *(float4*)(dst + (size_t)(b0 + i) * HDIM + n0l + 4) = o1;
  }
}

// per-sample hinge terms; folds code = tanh(sum_kb parts + bf). grid 128.
__global__ __launch_bounds__(256) void sims_kernel(
    const float* __restrict__ parts, const float* __restrict__ bfv,
    const float* __restrict__ da_pool, const float* __restrict__ dn_pool,
    float* __restrict__ terms) {
  __shared__ float sr[4][5];
  const int b = blockIdx.x, tid = threadIdx.x;
  float c2 = 0, a2 = 0, n2 = 0, ca = 0, cn = 0;
  for (int i = tid; i < HDIM; i += 256) {
    float pre = bfv[i];
#pragma unroll
    for (int kb = 0; kb < 16; ++kb)
      pre += parts[((size_t)kb * 128 + b) * HDIM + i];
    const float cf = fast_tanh(pre);
    const float av = fast_tanh(fast_tanh(da_pool[(size_t)b * HDIM + i]));
    const float nv = fast_tanh(fast_tanh(dn_pool[(size_t)b * HDIM + i]));
    c2 = fmaf(cf, cf, c2); a2 = fmaf(av, av, a2); n2 = fmaf(nv, nv, n2);
    ca = fmaf(cf, av, ca); cn = fmaf(cf, nv, cn);
  }
#pragma unroll
  for (int off = 32; off; off >>= 1) {
    c2 += __shfl_xor(c2, off); a2 += __shfl_xor(a2, off); n2 += __shfl_xor(n2, off);
    ca += __shfl_xor(ca, off); cn += __shfl_xor(cn, off);
  }
  const int wv = tid >> 6;
  if ((tid & 63) == 0) {
    sr[wv][0] = c2; sr[wv][1] = a2; sr[wv][2] = n2; sr[wv][3] = ca; sr[wv][4] = cn;
  }
  __syncthreads();
  if (tid == 0) {
    c2 = sr[0][0] + sr[1][0] + sr[2][0] + sr[3][0];
    a2 = sr[0][1] + sr[1][1] + sr[2][1] + sr[3][1];
    n2 = sr[0][2] + sr[1][2] + sr[2][2] + sr[3][2];
    ca = sr[0][3] + sr[1][3] + sr[2][3] + sr[3][3];
    cn = sr[0][4] + sr[1][4] + sr[2][4] + sr[3][4];
    const float nc = fmaxf(sqrtf(c2), 1e-8f);
    const float na = fmaxf(sqrtf(a2), 1e-8f);
    const float nn = fmaxf(sqrtf(n2), 1e-8f);
    terms[b] = fmaxf(0.05f - ca / (nc * na) + cn / (nc * nn), 1e-6f);
  }
}

__global__ void loss_kernel(const float* __restrict__ terms, float* __restrict__ out) {
  const int tid = threadIdx.x;  // 128
  float v = terms[tid];
#pragma unroll
  for (int off = 32; off; off >>= 1) v += __shfl_xor(v, off);
  __shared__ float sr[2];
  if ((tid & 63) == 0) sr[tid >> 6] = v;
  __syncthreads();
  if (tid == 0) out[0] = (sr[0] + sr[1]) * (1.0f / (float)BATCH);
}

// ===========================================================================

extern "C" void kernel_launch(void* const* d_in, const int* in_sizes, int n_in,
                              void* d_out, int out_size, void* d_ws, size_t ws_size,
                              hipStream_t stream) {
  (void)in_sizes; (void)n_in; (void)out_size; (void)ws_size;
  const float* token_feat = (const float*)d_in[0];
  const int*   token_len  = (const int*)d_in[1];
  const float* node_h     = (const float*)d_in[2];
  const int*   seg_ids    = (const int*)d_in[3];
  const float* da_feat    = (const float*)d_in[4];
  const int*   da_len     = (const int*)d_in[5];
  const float* dn_feat    = (const float*)d_in[6];
  const int*   dn_len     = (const int*)d_in[7];
  const float* Wt = (const float*)d_in[8];
  const float* bt = (const float*)d_in[9];
  const float* vt = (const float*)d_in[10];
  const float* Wa = (const float*)d_in[12];
  const float* ba = (const float*)d_in[13];
  const float* va = (const float*)d_in[14];
  const float* Wd = (const float*)d_in[16];
  const float* bd = (const float*)d_in[17];
  const float* vd = (const float*)d_in[18];
  const float* Wf  = (const float*)d_in[20];
  const float* bfv = (const float*)d_in[21];

  const int MTOK = 65536;
  const int MDESC2 = 32768;
  const int NNODES = 65536;

  float* ws = (float*)d_ws;
  float* logits_tok  = ws;                       // 65536 (atomic)
  float* logits_node = logits_tok + MTOK;        // 65536
  float* logits_desc = logits_node + NNODES;     // 32768 (da ++ dn)
  float* tok_pool    = logits_desc + MDESC2;
  float* ast_pool    = tok_pool + 128 * HDIM;
  float* da_pool     = ast_pool + 128 * HDIM;
  float* dn_pool     = da_pool + 128 * HDIM;
  float* terms       = dn_pool + 128 * HDIM;     // 128
  int*   seg_start   = (int*)(terms + 128);      // 256 slot
  float* parts       = (float*)(seg_start + 256);  // 16*128*512
  _Float16* W2t = (_Float16*)(parts + 16 * 128 * HDIM);
  _Float16* W2a = W2t + HDIM * HDIM;
  _Float16* W2d = W2a + HDIM * HDIM;

  // zero atomically-accumulated buffers: logits (160K) + pools (256K)
  const int ZTOT = MTOK + NNODES + MDESC2 + 4 * 128 * HDIM;
  zero_kernel<<<dim3((ZTOT + 255) / 256), 256, 0, stream>>>(ws, ZTOT);
  seg_bounds_kernel<<<1, 256, 0, stream>>>(seg_ids, NNODES, seg_start);
  cvt_w3_kernel<<<dim3(128, 3), 256, 0, stream>>>(Wt, Wa, Wd, W2t, W2a, W2d);

  // merged GEMM: 512 tok + 512 node + 128 da + 128 dn = 1280 blocks
  gemm_logits_merged2_kernel<<<1280, 512, 0, stream>>>(
      token_feat, node_h, da_feat, dn_feat, W2t, W2a, W2d,
      bt, vt, ba, va, bd, vd, logits_tok, logits_node, logits_desc);

  softmax_all_kernel<<<dim3(BATCH, 4), 256, 0, stream>>>(
      logits_tok, logits_desc, logits_node, token_len, da_len, dn_len, seg_start);

  pool_masked_all_kernel<<<dim3(BATCH, 12), 256, 0, stream>>>(
      token_feat, da_feat, dn_feat, logits_tok, logits_desc,
      tok_pool, da_pool, dn_pool);
  pool_seg_kernel<<<dim3(BATCH, 4), 256, 0, stream>>>(
      node_h, logits_node, seg_start, ast_pool);

  code_gemm_kernel<<<dim3(4, 16), 256, 0, stream>>>(tok_pool, ast_pool, Wf, parts);
  sims_kernel<<<BATCH, 256, 0, stream>>>(parts, bfv, da_pool, dn_pool, terms);
  loss_kernel<<<1, 128, 0, stream>>>(terms, (float*)d_out);
}

// Round 9
// 335.652 us; speedup vs baseline: 1.2280x; 1.2280x over previous
//
#include <hip/hip_runtime.h>
#include <math.h>

#define HDIM 512
#define BATCH 128

typedef _Float16 f16x8 __attribute__((ext_vector_type(8)));
typedef float f32x4 __attribute__((ext_vector_type(4)));

__device__ __forceinline__ float fast_tanh(float x) {
  float e = __expf(2.0f * x);
  return 1.0f - 2.0f / (e + 1.0f);
}

__device__ __forceinline__ void gload_lds16(const void* g, void* l) {
  __builtin_amdgcn_global_load_lds(
      (const __attribute__((address_space(1))) unsigned int*)g,
      (__attribute__((address_space(3))) unsigned int*)l, 16, 0, 0);
}

// ---------------------------------------------------------------------------
// Merged activation convert: A [Mrows][512] fp32 -> A2 [8 kt][Mtot][64] f16,
// rows XOR-swizzled (byte ^= (row&7)<<4). grid (2048, 4): y = segment.
// ---------------------------------------------------------------------------
__global__ __launch_bounds__(256) void cvt_all_kernel(
    const float* __restrict__ tok, const float* __restrict__ node,
    const float* __restrict__ da, const float* __restrict__ dn,
    _Float16* __restrict__ A2tok, _Float16* __restrict__ A2node,
    _Float16* __restrict__ A2desc) {
  const int seg = blockIdx.y;
  const float* A;
  _Float16* A2;
  int Mtot, m_off, Mrows;
  bool do_tanh = false;
  if (seg == 0)      { A = tok;  A2 = A2tok;  Mtot = 65536; m_off = 0;     Mrows = 65536; }
  else if (seg == 1) { A = node; A2 = A2node; Mtot = 65536; m_off = 0;     Mrows = 65536; do_tanh = true; }
  else if (seg == 2) { A = da;   A2 = A2desc; Mtot = 32768; m_off = 0;     Mrows = 16384; }
  else               { A = dn;   A2 = A2desc; Mtot = 32768; m_off = 16384; Mrows = 16384; }
  const int total = Mrows * 64;  // 16B chunks
  for (int i = blockIdx.x * 256 + threadIdx.x; i < total; i += gridDim.x * 256) {
    const int m = i >> 6, c = i & 63;
    const int kt = c >> 3, cc = c & 7;
    const float* src = A + (size_t)m * HDIM + c * 8;
    const float4 x = ((const float4*)src)[0];
    const float4 y = ((const float4*)src)[1];
    f16x8 h;
    if (do_tanh) {
      h[0] = (_Float16)fast_tanh(x.x); h[1] = (_Float16)fast_tanh(x.y);
      h[2] = (_Float16)fast_tanh(x.z); h[3] = (_Float16)fast_tanh(x.w);
      h[4] = (_Float16)fast_tanh(y.x); h[5] = (_Float16)fast_tanh(y.y);
      h[6] = (_Float16)fast_tanh(y.z); h[7] = (_Float16)fast_tanh(y.w);
    } else {
      h[0] = (_Float16)x.x; h[1] = (_Float16)x.y;
      h[2] = (_Float16)x.z; h[3] = (_Float16)x.w;
      h[4] = (_Float16)y.x; h[5] = (_Float16)y.y;
      h[6] = (_Float16)y.z; h[7] = (_Float16)y.w;
    }
    const int dr = m_off + m;
    char* dst = (char*)A2 + ((size_t)kt * Mtot + dr) * 128 + ((cc * 16) ^ ((dr & 7) << 4));
    *(f16x8*)dst = h;
  }
}

// W [512 k][512 n] fp32 -> W2 [8 kt][512 n][64 k] f16, XOR-swizzled by n.
__global__ __launch_bounds__(256) void cvt_w3_kernel(
    const float* __restrict__ Wt, const float* __restrict__ Wa,
    const float* __restrict__ Wd, _Float16* __restrict__ W2t,
    _Float16* __restrict__ W2a, _Float16* __restrict__ W2d) {
  const int i = blockIdx.x * 256 + threadIdx.x;  // 512*64
  if (i >= 512 * 64) return;
  const float* W = (blockIdx.y == 0) ? Wt : (blockIdx.y == 1) ? Wa : Wd;
  _Float16* W2 = (blockIdx.y == 0) ? W2t : (blockIdx.y == 1) ? W2a : W2d;
  const int n = i & 511, g = i >> 9;
  const int kt = g >> 3, cc = g & 7;
  f16x8 h;
#pragma unroll
  for (int j = 0; j < 8; ++j)
    h[j] = (_Float16)W[(size_t)(kt * 64 + cc * 8 + j) * HDIM + n];
  char* dst = (char*)W2 + ((size_t)kt * 512 + n) * 128 + ((cc * 16) ^ ((n & 7) << 4));
  *(f16x8*)dst = h;
}

// ---------------------------------------------------------------------------
// Merged fused logit GEMM — EXACT R6 (353 µs champion) internals, 1 dispatch.
//   logits[m] += sum_n v[n] * tanh( (A@W)[m,n] + bias[n] )   (+c skipped)
// A2: [8][M][64] swizzled f16; W2: [8][512][64] swizzled f16, both gload_lds.
// 256x256 tile, BK=64, 512 thr = 8 waves (2M x 4N), wave tile 128x64, acc 8x4.
// LDS 128 KB dbuf. Per K-tile: ph0 STAGE_A(t+1), vmcnt(4), barrier, HALF(ks0),
// barrier; ph1 STAGE_B(t+1), HALF(ks1), barrier. Never vmcnt(0) mid-loop.
// Segments: 512 tok + 512 node + 256 desc blocks = 1280 (XCD-bijective swz).
// ---------------------------------------------------------------------------
__global__ __launch_bounds__(512, 1) void gemm_logits_m_kernel(
    const _Float16* __restrict__ A2tok, const _Float16* __restrict__ A2node,
    const _Float16* __restrict__ A2desc,
    const _Float16* __restrict__ W2t, const _Float16* __restrict__ W2a,
    const _Float16* __restrict__ W2d,
    const float* __restrict__ bt, const float* __restrict__ vt,
    const float* __restrict__ ba, const float* __restrict__ va,
    const float* __restrict__ bd, const float* __restrict__ vd,
    float* __restrict__ logits_tok, float* __restrict__ logits_node,
    float* __restrict__ logits_desc) {
  __shared__ __align__(16) _Float16 As[2][256 * 64];  // 2 x 32 KB
  __shared__ __align__(16) _Float16 Bs[2][256 * 64];  // 2 x 32 KB

  const int tid = threadIdx.x;
  const int nwg = gridDim.x;
  const int qq = nwg >> 3;
  const int raw = (int)blockIdx.x;
  const int swz = (raw & 7) * qq + (raw >> 3);  // XCD-bijective (1280%8==0)

  int id, local;
  if (swz < 512)       { id = 0; local = swz; }
  else if (swz < 1024) { id = 1; local = swz - 512; }
  else                 { id = 2; local = swz - 1024; }
  const int mb = local >> 1, nb = local & 1;   // consecutive swz share A-panel
  const _Float16* A2 = (id == 0) ? A2tok : (id == 1) ? A2node : A2desc;
  const _Float16* W2 = (id == 0) ? W2t : (id == 1) ? W2a : W2d;
  const float* bias = (id == 0) ? bt : (id == 1) ? ba : bd;
  const float* vvec = (id == 0) ? vt : (id == 1) ? va : vd;
  float* logits = (id == 0) ? logits_tok : (id == 1) ? logits_node : logits_desc;
  const int M = (id == 2) ? 32768 : 65536;
  const size_t m0 = (size_t)mb * 256;
  const int n0 = nb * 256;

  const int lane = tid & 63, wid = tid >> 6;
  const int tx = lane & 15, qd = lane >> 4;
  const int wm = wid >> 2;   // 0..1 -> rows wm*128..+127
  const int wn = wid & 3;    // 0..3 -> cols wn*64..+63

  const char* gA = (const char*)A2 + m0 * 128;
  const char* gB = (const char*)W2 + (size_t)n0 * 128;
  const size_t sA = (size_t)M * 128;
  const size_t sB = (size_t)512 * 128;
  const int lo = tid * 16;       // per-lane global offset
  const int wlo = wid * 1024;    // wave-uniform LDS chunk base

  f32x4 acc[8][4];
#pragma unroll
  for (int i = 0; i < 8; ++i)
#pragma unroll
    for (int j = 0; j < 4; ++j) acc[i][j] = (f32x4){0.f, 0.f, 0.f, 0.f};

  auto STAGE_A = [&](int buf, int kt) {
    const char* a = gA + (size_t)kt * sA;
#pragma unroll
    for (int p = 0; p < 4; ++p)
      gload_lds16(a + lo + p * 8192, (char*)As[buf] + wlo + p * 8192);
  };
  auto STAGE_B = [&](int buf, int kt) {
    const char* b = gB + (size_t)kt * sB;
#pragma unroll
    for (int p = 0; p < 4; ++p)
      gload_lds16(b + lo + p * 8192, (char*)Bs[buf] + wlo + p * 8192);
  };

  auto HALF = [&](int buf, int ks) {
    f16x8 aF[8], bF[4];
#pragma unroll
    for (int i = 0; i < 8; ++i) {
      const int row = wm * 128 + i * 16 + tx;
      int by = row * 128 + (ks * 32 + qd * 8) * 2;
      by ^= (row & 7) << 4;
      aF[i] = *(const f16x8*)((const char*)As[buf] + by);
    }
#pragma unroll
    for (int j = 0; j < 4; ++j) {
      const int n = wn * 64 + j * 16 + tx;
      int by = n * 128 + (ks * 32 + qd * 8) * 2;
      by ^= (n & 7) << 4;
      bF[j] = *(const f16x8*)((const char*)Bs[buf] + by);
    }
    __builtin_amdgcn_s_setprio(1);
#pragma unroll
    for (int i = 0; i < 8; ++i)
#pragma unroll
      for (int j = 0; j < 4; ++j)
        acc[i][j] = __builtin_amdgcn_mfma_f32_16x16x32_f16(aF[i], bF[j], acc[i][j], 0, 0, 0);
    __builtin_amdgcn_s_setprio(0);
  };

  STAGE_A(0, 0);
  STAGE_B(0, 0);
#pragma unroll
  for (int t = 0; t < 8; ++t) {
    const int cur = t & 1;
    // --- phase 0 ---
    if (t < 7) {
      STAGE_A(cur ^ 1, t + 1);  // outstanding: 8 (tile t) + 4 (A of t+1)
      asm volatile("s_waitcnt vmcnt(4)" ::: "memory");  // drain tile t's 8
    } else {
      asm volatile("s_waitcnt vmcnt(0)" ::: "memory");
    }
    __builtin_amdgcn_s_barrier();
    asm volatile("" ::: "memory");
    HALF(cur, 0);
    asm volatile("" ::: "memory");
    __builtin_amdgcn_s_barrier();  // lockstep between phases
    asm volatile("" ::: "memory");
    // --- phase 1 ---
    if (t < 7) STAGE_B(cur ^ 1, t + 1);  // outstanding back to 8
    HALF(cur, 1);
    asm volatile("" ::: "memory");
    __builtin_amdgcn_s_barrier();  // all reads of buf[cur] done
    asm volatile("" ::: "memory");
  }

  // epilogue: t = tanh(acc + bias[n]) * v[n], reduce over this block's 256 n's
  float vv[4], bb[4];
#pragma unroll
  for (int j = 0; j < 4; ++j) {
    const int n = n0 + wn * 64 + j * 16 + tx;
    vv[j] = vvec[n];
    bb[j] = bias[n];
  }
#pragma unroll
  for (int i = 0; i < 8; ++i) {
#pragma unroll
    for (int r = 0; r < 4; ++r) {
      float s = 0.0f;
#pragma unroll
      for (int j = 0; j < 4; ++j)
        s = fmaf(vv[j], fast_tanh(acc[i][j][r] + bb[j]), s);
      s += __shfl_xor(s, 1);
      s += __shfl_xor(s, 2);
      s += __shfl_xor(s, 4);
      s += __shfl_xor(s, 8);
      if (tx == 0)
        atomicAdd(&logits[m0 + wm * 128 + i * 16 + qd * 4 + r], s);
    }
  }
}

// ---------------------------------------------------------------------------
// small/streaming kernels (identical to R6 champion)
// ---------------------------------------------------------------------------

__global__ void zero_kernel(float* __restrict__ p, int n) {
  const int i = blockIdx.x * 256 + threadIdx.x;
  if (i < n) p[i] = 0.0f;
}

__global__ void seg_bounds_kernel(const int* __restrict__ seg, int N,
                                  int* __restrict__ seg_start) {
  const int b = threadIdx.x;
  if (b > BATCH) return;
  int lo = 0, hi = N;
  while (lo < hi) {
    const int mid = (lo + hi) >> 1;
    if (seg[mid] < b) lo = mid + 1; else hi = mid;
  }
  seg_start[b] = lo;
}

// grid (128, 4): y=0 token (S=512), y=1 desc-anchor, y=2 desc-neg, y=3 node-seg
__global__ __launch_bounds__(256) void softmax_all_kernel(
    float* __restrict__ ltok, float* __restrict__ ldesc,
    float* __restrict__ lnode, const int* __restrict__ tlen,
    const int* __restrict__ dalen, const int* __restrict__ dnlen,
    const int* __restrict__ seg_start) {
  __shared__ float smax[4], ssum[4];
  const int b = blockIdx.x, mode = blockIdx.y, tid = threadIdx.x;
  float* l;
  int s0, s1, fill_end;
  if (mode == 0)      { l = ltok + (size_t)b * 512;          s0 = 0; s1 = tlen[b];  fill_end = 512; }
  else if (mode == 1) { l = ldesc + (size_t)b * 128;         s0 = 0; s1 = dalen[b]; fill_end = 128; }
  else if (mode == 2) { l = ldesc + 16384 + (size_t)b * 128; s0 = 0; s1 = dnlen[b]; fill_end = 128; }
  else                { l = lnode; s0 = seg_start[b]; s1 = seg_start[b + 1]; fill_end = -1; }

  float mymax = -1e30f;
  for (int s = s0 + tid; s < s1; s += 256) mymax = fmaxf(mymax, l[s]);
#pragma unroll
  for (int off = 32; off; off >>= 1) mymax = fmaxf(mymax, __shfl_xor(mymax, off));
  if ((tid & 63) == 0) smax[tid >> 6] = mymax;
  __syncthreads();
  const float bmax = fmaxf(fmaxf(smax[0], smax[1]), fmaxf(smax[2], smax[3]));
  float mysum = 0.0f;
  for (int s = s0 + tid; s < s1; s += 256) mysum += __expf(l[s] - bmax);
#pragma unroll
  for (int off = 32; off; off >>= 1) mysum += __shfl_xor(mysum, off);
  if ((tid & 63) == 0) ssum[tid >> 6] = mysum;
  __syncthreads();
  const float inv = 1.0f / (ssum[0] + ssum[1] + ssum[2] + ssum[3]);
  for (int s = s0 + tid; s < s1; s += 256) l[s] = __expf(l[s] - bmax) * inv;
  if (fill_end > 0)
    for (int s = s1 + tid; s < fill_end; s += 256) l[s] = 0.0f;
}

// grid (128, 12): c<8 token chunks, c in {8,9} desc-anchor, {10,11} desc-neg
__global__ __launch_bounds__(256) void pool_masked_all_kernel(
    const _Float16* __restrict__ A2tok, const _Float16* __restrict__ A2desc,
    const float* __restrict__ ltok, const float* __restrict__ ldesc,
    float* __restrict__ tok_pool, float* __restrict__ da_pool,
    float* __restrict__ dn_pool) {
  const int b = blockIdx.x, c = blockIdx.y, tid = threadIdx.x;
  const _Float16* A2;
  const float* w;
  float* out;
  int Mtot, rbase, s0;
  if (c < 8)       { A2 = A2tok;  Mtot = 65536; rbase = b * 512;         w = ltok;  out = tok_pool; s0 = c * 64; }
  else if (c < 10) { A2 = A2desc; Mtot = 32768; rbase = b * 128;         w = ldesc; out = da_pool;  s0 = (c - 8) * 64; }
  else             { A2 = A2desc; Mtot = 32768; rbase = 16384 + b * 128; w = ldesc; out = dn_pool;  s0 = (c - 10) * 64; }
  const int h = tid * 2;
  const int kt = h >> 6, col = h & 63;
  const char* base = (const char*)A2 + (size_t)kt * Mtot * 128;
  float ax = 0.0f, ay = 0.0f;
  for (int s = s0; s < s0 + 64; ++s) {
    const int row = rbase + s;
    const float wsc = w[row];
    if (wsc != 0.0f) {
      const unsigned u = *(const unsigned*)(base + (size_t)row * 128 + ((col * 2) ^ ((row & 7) << 4)));
      const _Float16* hp = (const _Float16*)&u;
      ax = fmaf(wsc, (float)hp[0], ax);
      ay = fmaf(wsc, (float)hp[1], ay);
    }
  }
  atomicAdd(&out[b * HDIM + h], ax);
  atomicAdd(&out[b * HDIM + h + 1], ay);
}

// ast_pool[b,h] += sum_{n in seg b} w[n] * A2node[n,h] (tanh pre-applied)
__global__ __launch_bounds__(256) void pool_tiled_seg_kernel(
    const _Float16* __restrict__ A2, const float* __restrict__ w,
    const int* __restrict__ seg_start, float* __restrict__ pool, int Mtot) {
  const int b = blockIdx.x, c = blockIdx.y, tid = threadIdx.x;
  const int h = tid * 2;
  const int kt = h >> 6, col = h & 63;
  const char* base = (const char*)A2 + (size_t)kt * Mtot * 128;
  const int s0 = seg_start[b], s1 = seg_start[b + 1];
  const int nseg = s1 - s0;
  const int chunk = (nseg + (int)gridDim.y - 1) / (int)gridDim.y;
  const int a0 = s0 + c * chunk;
  const int a1 = min(s1, a0 + chunk);
  float ax = 0.0f, ay = 0.0f;
  for (int s = a0; s < a1; ++s) {
    const float wsc = w[s];
    const unsigned u = *(const unsigned*)(base + (size_t)s * 128 + ((col * 2) ^ ((s & 7) << 4)));
    const _Float16* hp = (const _Float16*)&u;
    ax = fmaf(wsc, (float)hp[0], ax);
    ay = fmaf(wsc, (float)hp[1], ay);
  }
  atomicAdd(&pool[b * HDIM + h], ax);
  atomicAdd(&pool[b * HDIM + h + 1], ay);
}

// code-pre GEMM: parts[kb][b][n-chunk] = tanh(cat)[b][k-chunk] @ Wf[k-chunk][n-chunk]
__global__ __launch_bounds__(256) void code_gemm_kernel(
    const float* __restrict__ tok_pool, const float* __restrict__ ast_pool,
    const float* __restrict__ Wf, float* __restrict__ parts) {
  __shared__ float catS[128][65];
  __shared__ float4 wfS[64][32];
  const int nb = blockIdx.x, kb = blockIdx.y, tid = threadIdx.x;
  const int k0 = kb * 64;
  const float* src = (k0 < 512) ? (tok_pool + k0) : (ast_pool + (k0 - 512));
  for (int i = tid; i < 128 * 16; i += 256) {
    const int r = i >> 4, c4 = i & 15;
    const float4 v = *(const float4*)(src + (size_t)r * HDIM + c4 * 4);
    catS[r][c4 * 4 + 0] = fast_tanh(v.x);
    catS[r][c4 * 4 + 1] = fast_tanh(v.y);
    catS[r][c4 * 4 + 2] = fast_tanh(v.z);
    catS[r][c4 * 4 + 3] = fast_tanh(v.w);
  }
  for (int i = tid; i < 64 * 32; i += 256) {
    const int r = i >> 5, c = i & 31;
    wfS[r][c] = *(const float4*)(Wf + (size_t)(k0 + r) * HDIM + nb * 128 + c * 4);
  }
  __syncthreads();
  const int tb = tid >> 4, tn = tid & 15;
  const int b0 = tb * 8, n0l = tn * 8;
  float acc[8][8];
#pragma unroll
  for (int i = 0; i < 8; ++i)
#pragma unroll
    for (int j = 0; j < 8; ++j) acc[i][j] = 0.0f;
  for (int k = 0; k < 64; ++k) {
    float a[8];
#pragma unroll
    for (int i = 0; i < 8; ++i) a[i] = catS[b0 + i][k];
    const float4 w0 = wfS[k][tn * 2], w1 = wfS[k][tn * 2 + 1];
    const float wv[8] = {w0.x, w0.y, w0.z, w0.w, w1.x, w1.y, w1.z, w1.w};
#pragma unroll
    for (int i = 0; i < 8; ++i)
#pragma unroll
      for (int j = 0; j < 8; ++j) acc[i][j] = fmaf(a[i], wv[j], acc[i][j]);
  }
  float* dst = parts + ((size_t)kb * 128) * HDIM + nb * 128;
#pragma unroll
  for (int i = 0; i < 8; ++i) {
    const float4 o0 = {acc[i][0], acc[i][1], acc[i][2], acc[i][3]};
    const float4 o1 = {acc[i][4], acc[i][5], acc[i][6], acc[i][7]};
    *(float4*)(dst + (size_t)(b0 + i) * HDIM + n0l) = o0;
    *(float4*)(dst + (size_t)(b0 + i) * HDIM + n0l + 4) = o1;
  }
}

// per-sample hinge terms; folds code = tanh(sum_kb parts + bf). grid 128.
__global__ __launch_bounds__(256) void sims_kernel(
    const float* __restrict__ parts, const float* __restrict__ bfv,
    const float* __restrict__ da_pool, const float* __restrict__ dn_pool,
    float* __restrict__ terms) {
  __shared__ float sr[4][5];
  const int b = blockIdx.x, tid = threadIdx.x;
  float c2 = 0, a2 = 0, n2 = 0, ca = 0, cn = 0;
  for (int i = tid; i < HDIM; i += 256) {
    float pre = bfv[i];
#pragma unroll
    for (int kb = 0; kb < 16; ++kb)
      pre += parts[((size_t)kb * 128 + b) * HDIM + i];
    const float cf = fast_tanh(pre);
    const float av = fast_tanh(fast_tanh(da_pool[(size_t)b * HDIM + i]));
    const float nv = fast_tanh(fast_tanh(dn_pool[(size_t)b * HDIM + i]));
    c2 = fmaf(cf, cf, c2); a2 = fmaf(av, av, a2); n2 = fmaf(nv, nv, n2);
    ca = fmaf(cf, av, ca); cn = fmaf(cf, nv, cn);
  }
#pragma unroll
  for (int off = 32; off; off >>= 1) {
    c2 += __shfl_xor(c2, off); a2 += __shfl_xor(a2, off); n2 += __shfl_xor(n2, off);
    ca += __shfl_xor(ca, off); cn += __shfl_xor(cn, off);
  }
  const int wv = tid >> 6;
  if ((tid & 63) == 0) {
    sr[wv][0] = c2; sr[wv][1] = a2; sr[wv][2] = n2; sr[wv][3] = ca; sr[wv][4] = cn;
  }
  __syncthreads();
  if (tid == 0) {
    c2 = sr[0][0] + sr[1][0] + sr[2][0] + sr[3][0];
    a2 = sr[0][1] + sr[1][1] + sr[2][1] + sr[3][1];
    n2 = sr[0][2] + sr[1][2] + sr[2][2] + sr[3][2];
    ca = sr[0][3] + sr[1][3] + sr[2][3] + sr[3][3];
    cn = sr[0][4] + sr[1][4] + sr[2][4] + sr[3][4];
    const float nc = fmaxf(sqrtf(c2), 1e-8f);
    const float na = fmaxf(sqrtf(a2), 1e-8f);
    const float nn = fmaxf(sqrtf(n2), 1e-8f);
    terms[b] = fmaxf(0.05f - ca / (nc * na) + cn / (nc * nn), 1e-6f);
  }
}

__global__ void loss_kernel(const float* __restrict__ terms, float* __restrict__ out) {
  const int tid = threadIdx.x;  // 128
  float v = terms[tid];
#pragma unroll
  for (int off = 32; off; off >>= 1) v += __shfl_xor(v, off);
  __shared__ float sr[2];
  if ((tid & 63) == 0) sr[tid >> 6] = v;
  __syncthreads();
  if (tid == 0) out[0] = (sr[0] + sr[1]) * (1.0f / (float)BATCH);
}

// ===========================================================================

extern "C" void kernel_launch(void* const* d_in, const int* in_sizes, int n_in,
                              void* d_out, int out_size, void* d_ws, size_t ws_size,
                              hipStream_t stream) {
  (void)in_sizes; (void)n_in; (void)out_size; (void)ws_size;
  const float* token_feat = (const float*)d_in[0];
  const int*   token_len  = (const int*)d_in[1];
  const float* node_h     = (const float*)d_in[2];
  const int*   seg_ids    = (const int*)d_in[3];
  const float* da_feat    = (const float*)d_in[4];
  const int*   da_len     = (const int*)d_in[5];
  const float* dn_feat    = (const float*)d_in[6];
  const int*   dn_len     = (const int*)d_in[7];
  const float* Wt = (const float*)d_in[8];
  const float* bt = (const float*)d_in[9];
  const float* vt = (const float*)d_in[10];
  const float* Wa = (const float*)d_in[12];
  const float* ba = (const float*)d_in[13];
  const float* va = (const float*)d_in[14];
  const float* Wd = (const float*)d_in[16];
  const float* bd = (const float*)d_in[17];
  const float* vd = (const float*)d_in[18];
  const float* Wf  = (const float*)d_in[20];
  const float* bfv = (const float*)d_in[21];

  const int MTOK = 65536;
  const int MDESC2 = 32768;
  const int NNODES = 65536;

  float* ws = (float*)d_ws;
  float* logits_tok  = ws;                       // 65536 (atomic)
  float* logits_node = logits_tok + MTOK;        // 65536
  float* logits_desc = logits_node + NNODES;     // 32768 (da ++ dn)
  float* tok_pool    = logits_desc + MDESC2;
  float* ast_pool    = tok_pool + 128 * HDIM;
  float* da_pool     = ast_pool + 128 * HDIM;
  float* dn_pool     = da_pool + 128 * HDIM;
  float* terms       = dn_pool + 128 * HDIM;     // 128
  int*   seg_start   = (int*)(terms + 128);      // 256 slot
  float* parts       = (float*)(seg_start + 256);  // 16*128*512
  _Float16* W2t = (_Float16*)(parts + 16 * 128 * HDIM);
  _Float16* W2a = W2t + HDIM * HDIM;
  _Float16* W2d = W2a + HDIM * HDIM;
  _Float16* A2tok  = W2d + HDIM * HDIM;               // 8*65536*64 f16
  _Float16* A2node = A2tok + (size_t)8 * MTOK * 64;
  _Float16* A2desc = A2node + (size_t)8 * NNODES * 64;  // 8*32768*64 f16

  // zero atomically-accumulated buffers: logits + pools
  const int ZTOT = MTOK + NNODES + MDESC2 + 4 * 128 * HDIM;
  zero_kernel<<<dim3((ZTOT + 255) / 256), 256, 0, stream>>>(ws, ZTOT);
  seg_bounds_kernel<<<1, 256, 0, stream>>>(seg_ids, NNODES, seg_start);

  // convert weights + activations to tiled swizzled f16 (2 launches)
  cvt_w3_kernel<<<dim3(128, 3), 256, 0, stream>>>(Wt, Wa, Wd, W2t, W2a, W2d);
  cvt_all_kernel<<<dim3(2048, 4), 256, 0, stream>>>(
      token_feat, node_h, da_feat, dn_feat, A2tok, A2node, A2desc);

  // ONE merged GEMM: 512 tok + 512 node + 256 desc = 1280 blocks (R6 internals)
  gemm_logits_m_kernel<<<1280, 512, 0, stream>>>(
      A2tok, A2node, A2desc, W2t, W2a, W2d,
      bt, vt, ba, va, bd, vd, logits_tok, logits_node, logits_desc);

  softmax_all_kernel<<<dim3(BATCH, 4), 256, 0, stream>>>(
      logits_tok, logits_desc, logits_node, token_len, da_len, dn_len, seg_start);

  pool_masked_all_kernel<<<dim3(BATCH, 12), 256, 0, stream>>>(
      A2tok, A2desc, logits_tok, logits_desc, tok_pool, da_pool, dn_pool);
  pool_tiled_seg_kernel<<<dim3(BATCH, 4), 256, 0, stream>>>(
      A2node, logits_node, seg_start, ast_pool, NNODES);

  code_gemm_kernel<<<dim3(4, 16), 256, 0, stream>>>(tok_pool, ast_pool, Wf, parts);
  sims_kernel<<<BATCH, 256, 0, stream>>>(parts, bfv, da_pool, dn_pool, terms);
  loss_kernel<<<1, 128, 0, stream>>>(terms, (float*)d_out);
}